// Round 13
// baseline (1176.156 us; speedup 1.0000x reference)
//
#include <hip/hip_runtime.h>
#include <hip/hip_bf16.h>
#include <hip/hip_cooperative_groups.h>
#include <cstdint>
#include <cstddef>

namespace cg = cooperative_groups;

#define N_NODES 50000
#define DIM 512
#define N_EDGES 1600000
#define NT 25           // column tiles of 2048 nodes
#define NB (N_NODES * NT)
#define NCHUNK ((NB + 1023) / 1024)   // 1221
#define GPANELS 391     // ceil(50000/128) row panels in gemm
#define NSHAD 8         // shadow copies for reduce atomics
#define CSR_BLOCKS 1024
#define CSR_THREADS 256

typedef __bf16 bf16;
typedef __bf16 bf16x8 __attribute__((ext_vector_type(8)));
typedef __bf16 bf16x4 __attribute__((ext_vector_type(4)));
typedef float floatx4 __attribute__((ext_vector_type(4)));

// ---------------- prep: cast x & w to bf16, zero cnt + stat buffers + done ----------
__global__ void prep_kernel(const float* __restrict__ x, bf16* __restrict__ xb,
                            const float* __restrict__ w, bf16* __restrict__ wb,
                            int4* __restrict__ cnt4, float4* __restrict__ stats4,
                            int n4x, int n4w) {
    int i = blockIdx.x * blockDim.x + threadIdx.x;
    if (i < n4x) {
        float4 v = reinterpret_cast<const float4*>(x)[i];
        bf16x4 o;
        o[0] = (bf16)v.x; o[1] = (bf16)v.y; o[2] = (bf16)v.z; o[3] = (bf16)v.w;
        reinterpret_cast<bf16x4*>(xb)[i] = o;
    }
    if (i < n4w) {
        float4 v = reinterpret_cast<const float4*>(w)[i];
        bf16x4 o;
        o[0] = (bf16)v.x; o[1] = (bf16)v.y; o[2] = (bf16)v.z; o[3] = (bf16)v.w;
        reinterpret_cast<bf16x4*>(wb)[i] = o;
    }
    if (i < NB / 4) cnt4[i] = make_int4(0, 0, 0, 0);
    // colsumS[4096 floats] + totsqS[8] + done: 1028 float4 covers all
    if (i < 1028) stats4[i] = make_float4(0.f, 0.f, 0.f, 0.f);
}

// ---------------- cooperative CSR build: hist -> scan -> scatter, ONE dispatch ------
// Replaces 5 dispatches (hist, scanA, scanB, scanC, scatter). Phases separated by
// grid.sync(); 1024 blocks x 256 thr = 4 blk/CU, co-residency guaranteed by coop launch.
__device__ void scan_chunk_1024(int cb, const int* __restrict__ cnt,
                                int* __restrict__ row_start, int* __restrict__ blksum) {
    const int t = threadIdx.x;  // 0..255, 4 elems each
    const int i0 = cb * 1024 + t * 4;
    int v0 = (i0 + 0 < NB) ? cnt[i0 + 0] : 0;
    int v1 = (i0 + 1 < NB) ? cnt[i0 + 1] : 0;
    int v2 = (i0 + 2 < NB) ? cnt[i0 + 2] : 0;
    int v3 = (i0 + 3 < NB) ? cnt[i0 + 3] : 0;
    const int tsum = v0 + v1 + v2 + v3;
    int s = tsum;
#pragma unroll
    for (int off = 1; off < 64; off <<= 1) {
        int u = __shfl_up(s, off, 64);
        if ((t & 63) >= off) s += u;
    }
    __shared__ int ws[4];
    if ((t & 63) == 63) ws[t >> 6] = s;
    __syncthreads();
    int wbase = 0;
#pragma unroll
    for (int w = 0; w < 4; w++)
        if ((t >> 6) > w) wbase += ws[w];
    const int excl = wbase + s - tsum;  // exclusive prefix of this thread's first elem
    if (i0 + 0 < NB) row_start[i0 + 0] = excl;
    if (i0 + 1 < NB) row_start[i0 + 1] = excl + v0;
    if (i0 + 2 < NB) row_start[i0 + 2] = excl + v0 + v1;
    if (i0 + 3 < NB) row_start[i0 + 3] = excl + v0 + v1 + v2;
    if (t == 255) blksum[cb] = wbase + s;  // chunk total
    __syncthreads();  // ws reused next iteration
}

__device__ void scan_blksum_block0(const int* __restrict__ blksum, int* __restrict__ blkoff) {
    const int t = threadIdx.x;  // 5 entries/thread, 1221 <= 1280
    int c[5];
    int tsum = 0;
#pragma unroll
    for (int j = 0; j < 5; j++) {
        int idx = t * 5 + j;
        c[j] = (idx < NCHUNK) ? blksum[idx] : 0;
        tsum += c[j];
    }
    int s = tsum;
#pragma unroll
    for (int off = 1; off < 64; off <<= 1) {
        int u = __shfl_up(s, off, 64);
        if ((t & 63) >= off) s += u;
    }
    __shared__ int ws2[4];
    if ((t & 63) == 63) ws2[t >> 6] = s;
    __syncthreads();
    int wbase = 0;
#pragma unroll
    for (int w = 0; w < 4; w++)
        if ((t >> 6) > w) wbase += ws2[w];
    int excl = wbase + s - tsum;
#pragma unroll
    for (int j = 0; j < 5; j++) {
        int idx = t * 5 + j;
        if (idx < NCHUNK) blkoff[idx] = excl;
        excl += c[j];
    }
}

__global__ void csr_kernel(const int* __restrict__ rows, const int* __restrict__ cols,
                           const float* __restrict__ vals, int* __restrict__ cnt,
                           int* __restrict__ row_start, int* __restrict__ blksum,
                           int* __restrict__ blkoff, int* __restrict__ rowb,
                           int2* __restrict__ ecv) {
    cg::grid_group grid = cg::this_grid();
    const int tid = blockIdx.x * CSR_THREADS + threadIdx.x;
    const int nthr = CSR_BLOCKS * CSR_THREADS;  // 262144

    // P1: histogram (cnt zeroed by prep, prior dispatch)
    for (int i = tid; i < N_EDGES; i += nthr) {
        int key = rows[i] * NT + (cols[i] >> 11);
        atomicAdd(&cnt[key], 1);
    }
    grid.sync();

    // P2: per-chunk exclusive scan (chunks of 1024)
    for (int cb = blockIdx.x; cb < NCHUNK; cb += CSR_BLOCKS)
        scan_chunk_1024(cb, cnt, row_start, blksum);
    grid.sync();

    // P3: scan of chunk totals (block 0 only)
    if (blockIdx.x == 0) scan_blksum_block0(blksum, blkoff);
    grid.sync();

    // P4: apply chunk offsets; extract per-row bounds (rowb) for spmm
    for (int i = tid; i < NB; i += nthr) {
        int v = row_start[i] + blkoff[i >> 10];
        row_start[i] = v;
        if (i % NT == 0) rowb[i / NT] = v;
    }
    if (tid == 0) rowb[N_NODES] = N_EDGES;
    grid.sync();

    // P5: scatter (row_start doubles as cursor; spmm uses rowb only)
    for (int i = tid; i < N_EDGES; i += nthr) {
        int c = cols[i];
        int key = rows[i] * NT + (c >> 11);
        int p = atomicAdd(&row_start[key], 1);
        ecv[p] = make_int2(c, __float_as_int(vals[i]));
    }
}

// ---------------- GEMM (R10 single-buffer, proven ~80us measured R12) ----------------
__global__ __launch_bounds__(256) void gemm_kernel(const bf16* __restrict__ A,
                                                   const bf16* __restrict__ B,
                                                   bf16* __restrict__ C) {
    __shared__ bf16 lA[128 * 32];
    __shared__ bf16 lB[128 * 32];
    const int d = blockIdx.x;
    const int p = (d & 7) + ((d >> 5) << 3);  // row panel (XCD-chunked swizzle)
    const int c = (d >> 3) & 3;               // col tile
    if (p >= GPANELS) return;
    const int t = threadIdx.x;
    const int wave = t >> 6;
    const int lane = t & 63;
    const int rowBase = p * 128;
    const int colBase = c * 128;
    const int wm = (wave >> 1) * 64;
    const int wn = (wave & 1) * 64;
    floatx4 acc[4][4] = {};

    const int r_a = t >> 2;
    const int kk = (t & 3) * 8;
    const int l15 = lane & 15;
    const int koff = (lane >> 4) * 8;

    for (int k0 = 0; k0 < DIM; k0 += 32) {
#pragma unroll
        for (int j = 0; j < 2; j++) {
            int row = rowBase + r_a + j * 64;
            if (row > N_NODES - 1) row = N_NODES - 1;
            const bf16* g = A + (size_t)row * DIM + k0 + kk;
            bf16* l = lA + wave * 512 + j * 2048;
            __builtin_amdgcn_global_load_lds(
                (const __attribute__((address_space(1))) void*)g,
                (__attribute__((address_space(3))) void*)l, 16, 0, 0);
        }
#pragma unroll
        for (int j = 0; j < 2; j++) {
            int row = colBase + r_a + j * 64;
            const bf16* g = B + (size_t)row * DIM + k0 + kk;
            bf16* l = lB + wave * 512 + j * 2048;
            __builtin_amdgcn_global_load_lds(
                (const __attribute__((address_space(1))) void*)g,
                (__attribute__((address_space(3))) void*)l, 16, 0, 0);
        }
        __syncthreads();
        bf16x8 af[4], bfr[4];
#pragma unroll
        for (int i = 0; i < 4; i++)
            af[i] = *reinterpret_cast<const bf16x8*>(lA + (wm + i * 16 + l15) * 32 + koff);
#pragma unroll
        for (int j = 0; j < 4; j++)
            bfr[j] = *reinterpret_cast<const bf16x8*>(lB + (wn + j * 16 + l15) * 32 + koff);
#pragma unroll
        for (int i = 0; i < 4; i++)
#pragma unroll
            for (int j = 0; j < 4; j++)
                acc[i][j] = __builtin_amdgcn_mfma_f32_16x16x32_bf16(af[i], bfr[j], acc[i][j], 0, 0, 0);
        __syncthreads();
    }
    const int rquad = (lane >> 4) * 4;
#pragma unroll
    for (int i = 0; i < 4; i++) {
#pragma unroll
        for (int reg = 0; reg < 4; reg++) {
            int gr = rowBase + wm + i * 16 + rquad + reg;
            if (gr >= N_NODES) continue;
#pragma unroll
            for (int j = 0; j < 4; j++) {
                int gc = colBase + wn + j * 16 + l15;
                C[(size_t)gr * DIM + gc] = (bf16)acc[i][j][reg];
            }
        }
    }
}

// ---------------- SpMM (v1, measured best ~228us; now reads rowb) ----------------
__device__ __forceinline__ float blo(uint32_t w) { return __uint_as_float(w << 16); }
__device__ __forceinline__ float bhi(uint32_t w) { return __uint_as_float(w & 0xffff0000u); }

__device__ __forceinline__ void fmac8(float* acc, float v, const uint4& w) {
    acc[0] += v * blo(w.x); acc[1] += v * bhi(w.x);
    acc[2] += v * blo(w.y); acc[3] += v * bhi(w.y);
    acc[4] += v * blo(w.z); acc[5] += v * bhi(w.z);
    acc[6] += v * blo(w.w); acc[7] += v * bhi(w.w);
}

__global__ __launch_bounds__(256) void spmm_kernel(const int* __restrict__ rowb,
                                                   const int2* __restrict__ ecv,
                                                   const bf16* __restrict__ y,
                                                   float* __restrict__ y2) {
    const int wave = threadIdx.x >> 6;
    const int lane = threadIdx.x & 63;
    const int r = blockIdx.x * 4 + wave;  // grid = 12500 exactly
    const int s = rowb[r];
    const int e = rowb[r + 1];
    float acc[8] = {0.f, 0.f, 0.f, 0.f, 0.f, 0.f, 0.f, 0.f};
    const uint32_t* yb = reinterpret_cast<const uint32_t*>(y);

    int i = s;
    for (; i + 3 < e; i += 4) {
        int2 e0 = ecv[i], e1 = ecv[i + 1], e2 = ecv[i + 2], e3 = ecv[i + 3];
        uint4 w0 = *reinterpret_cast<const uint4*>(yb + (size_t)e0.x * 256 + lane * 4);
        uint4 w1 = *reinterpret_cast<const uint4*>(yb + (size_t)e1.x * 256 + lane * 4);
        uint4 w2 = *reinterpret_cast<const uint4*>(yb + (size_t)e2.x * 256 + lane * 4);
        uint4 w3 = *reinterpret_cast<const uint4*>(yb + (size_t)e3.x * 256 + lane * 4);
        fmac8(acc, __int_as_float(e0.y), w0);
        fmac8(acc, __int_as_float(e1.y), w1);
        fmac8(acc, __int_as_float(e2.y), w2);
        fmac8(acc, __int_as_float(e3.y), w3);
    }
    for (; i < e; i++) {
        int2 e0 = ecv[i];
        uint4 w0 = *reinterpret_cast<const uint4*>(yb + (size_t)e0.x * 256 + lane * 4);
        fmac8(acc, __int_as_float(e0.y), w0);
    }
    float4* out = reinterpret_cast<float4*>(y2 + (size_t)r * DIM + lane * 8);
    out[0] = make_float4(acc[0], acc[1], acc[2], acc[3]);
    out[1] = make_float4(acc[4], acc[5], acc[6], acc[7]);
}

// ---------------- reduction + fused scalar (last-block ticket; R12-proven) ----------
#define RED_GRID 512
#define RED_CHUNK 16
__global__ __launch_bounds__(256) void reduce_kernel(const float* __restrict__ y2,
                                                     float* __restrict__ colsumS,
                                                     float* __restrict__ totsqS,
                                                     int* __restrict__ done,
                                                     const float* __restrict__ scale,
                                                     float* __restrict__ sfac,
                                                     float* __restrict__ colsum) {
    const int t = threadIdx.x;
    const int d2 = t * 2;
    float c0 = 0.f, c1 = 0.f, sq = 0.f;
    for (int r0 = blockIdx.x * RED_CHUNK; r0 < N_NODES; r0 += RED_GRID * RED_CHUNK) {
        float2 v[RED_CHUNK];
#pragma unroll
        for (int j = 0; j < RED_CHUNK; j++) {
            int r = r0 + j;
            v[j] = (r < N_NODES)
                       ? *reinterpret_cast<const float2*>(y2 + (size_t)r * DIM + d2)
                       : make_float2(0.f, 0.f);
        }
#pragma unroll
        for (int j = 0; j < RED_CHUNK; j++) {
            c0 += v[j].x;
            c1 += v[j].y;
            sq += v[j].x * v[j].x + v[j].y * v[j].y;
        }
    }
    const int sh = blockIdx.x & (NSHAD - 1);
    atomicAdd(&colsumS[sh * DIM + d2], c0);
    atomicAdd(&colsumS[sh * DIM + d2 + 1], c1);
    __shared__ float ssq[256];
    ssq[t] = sq;
    __syncthreads();
    for (int off = 128; off > 0; off >>= 1) {
        if (t < off) ssq[t] += ssq[t + off];
        __syncthreads();
    }
    if (t == 0) atomicAdd(&totsqS[sh], ssq[0]);

    __threadfence();
    __shared__ int ticket_s;
    if (t == 0) ticket_s = atomicAdd(done, 1);
    __syncthreads();
    if (ticket_s != RED_GRID - 1) return;
    float s0 = 0.f, s1 = 0.f;
#pragma unroll
    for (int c = 0; c < NSHAD; c++) {
        s0 += atomicAdd(&colsumS[c * DIM + t], 0.f);
        s1 += atomicAdd(&colsumS[c * DIM + t + 256], 0.f);
    }
    colsum[t] = s0;
    colsum[t + 256] = s1;
    float mu0 = s0 * (1.0f / N_NODES);
    float mu1 = s1 * (1.0f / N_NODES);
    __syncthreads();
    ssq[t] = mu0 * mu0 + mu1 * mu1;
    __syncthreads();
    for (int off = 128; off > 0; off >>= 1) {
        if (t < off) ssq[t] += ssq[t + off];
        __syncthreads();
    }
    if (t == 0) {
        float tq = 0.f;
#pragma unroll
        for (int c = 0; c < NSHAD; c++) tq += atomicAdd(&totsqS[c], 0.f);
        float var = tq * (1.0f / N_NODES) - ssq[0];
        sfac[0] = rsqrtf(var) * (1.0f + scale[0]) * sqrtf((float)DIM);
    }
}

// ---------------- final: out = relu((y2 - mu) * s) + x ----------------
__global__ void final_kernel(float* __restrict__ y2, const float* __restrict__ x,
                             const float* __restrict__ colsum, const float* __restrict__ sfac,
                             int n4) {
    int i = blockIdx.x * blockDim.x + threadIdx.x;
    if (i >= n4) return;
    const float invN = 1.0f / N_NODES;
    float4 v = reinterpret_cast<float4*>(y2)[i];
    float4 xv = reinterpret_cast<const float4*>(x)[i];
    float4 mu = reinterpret_cast<const float4*>(colsum)[i & 127];
    float s = sfac[0];
    v.x = fmaxf((v.x - mu.x * invN) * s, 0.0f) + xv.x;
    v.y = fmaxf((v.y - mu.y * invN) * s, 0.0f) + xv.y;
    v.z = fmaxf((v.z - mu.z * invN) * s, 0.0f) + xv.z;
    v.w = fmaxf((v.w - mu.w * invN) * s, 0.0f) + xv.w;
    reinterpret_cast<float4*>(y2)[i] = v;
}

extern "C" void kernel_launch(void* const* d_in, const int* in_sizes, int n_in,
                              void* d_out, int out_size, void* d_ws, size_t ws_size,
                              hipStream_t stream) {
    const float* x        = (const float*)d_in[0];
    const int*   adj_rows = (const int*)d_in[1];
    const int*   adj_cols = (const int*)d_in[2];
    const float* adj_vals = (const float*)d_in[3];
    const float* weight   = (const float*)d_in[4];
    const float* scale    = (const float*)d_in[5];
    float* out = (float*)d_out;  // doubles as y2 buffer

    char* ws = (char*)d_ws;
    size_t off = 0;
    auto alloc = [&](size_t b) {
        char* p = ws + off;
        off += (b + 255) & ~(size_t)255;
        return p;
    };
    bf16*  xb        = (bf16*)alloc((size_t)N_NODES * DIM * 2);   // 51.2 MB
    int2*  ecv       = (int2*)xb;  // ALIAS: gemm (reader of xb) completes before csr P5 writes
    bf16*  Wb        = (bf16*)alloc((size_t)DIM * DIM * 2);       // 0.5 MB
    bf16*  y         = (bf16*)alloc((size_t)N_NODES * DIM * 2);   // 51.2 MB
    int*   cnt       = (int*)alloc((size_t)NB * 4);               // 5 MB
    int*   row_start = (int*)alloc((size_t)(NB + 1) * 4);         // 5 MB (scan result + cursor)
    int*   blksum    = (int*)alloc((size_t)NCHUNK * 4);
    int*   blkoff    = (int*)alloc((size_t)NCHUNK * 4);
    int*   rowb      = (int*)alloc((size_t)(N_NODES + 1) * 4);    // 200 KB row bounds for spmm
    float* colsumS   = (float*)alloc((size_t)NSHAD * DIM * 4);    // 16 KB
    float* totsqS    = (float*)alloc((size_t)NSHAD * 4);          // done lives after totsqS
    int*   done      = (int*)(totsqS + NSHAD);
    float* colsum    = (float*)alloc(512 * 4);
    float* sfac      = (float*)alloc(4);
    (void)ws_size; (void)in_sizes; (void)n_in; (void)out_size;

    const int n4x = N_NODES * DIM / 4;  // 6,400,000
    const int n4w = DIM * DIM / 4;      // 65,536

    // 1) casts + cnt zero + stats/done zero
    prep_kernel<<<(n4x + 255) / 256, 256, 0, stream>>>(x, xb, weight, Wb,
                                                       (int4*)cnt, (float4*)colsumS,
                                                       n4x, n4w);

    // 2) GEMM (frees xb so ecv can alias it in the csr kernel)
    gemm_kernel<<<1568, 256, 0, stream>>>(xb, Wb, y);

    // 3) cooperative CSR build: hist + scans + scatter in ONE dispatch
    {
        void* args[] = {(void*)&adj_rows, (void*)&adj_cols, (void*)&adj_vals,
                        (void*)&cnt, (void*)&row_start, (void*)&blksum,
                        (void*)&blkoff, (void*)&rowb, (void*)&ecv};
        hipLaunchCooperativeKernel((void*)csr_kernel, dim3(CSR_BLOCKS),
                                   dim3(CSR_THREADS), args, 0, stream);
    }

    // 4) SpMM
    spmm_kernel<<<N_NODES / 4, 256, 0, stream>>>(rowb, ecv, y, out);

    // 5) reduce + fused scalar
    reduce_kernel<<<RED_GRID, 256, 0, stream>>>(out, colsumS, totsqS, done, scale, sfac, colsum);

    // 6) final
    final_kernel<<<(n4x + 255) / 256, 256, 0, stream>>>(out, x, colsum, sfac, n4x);
}

// Round 14
// 680.991 us; speedup vs baseline: 1.7271x; 1.7271x over previous
//
#include <hip/hip_runtime.h>
#include <hip/hip_bf16.h>
#include <cstdint>
#include <cstddef>

#define N_NODES 50000
#define DIM 512
#define N_EDGES 1600000
#define NT 25           // column tiles of 2048 nodes
#define NB (N_NODES * NT)          // 1,250,000 buckets
#define NWORDS (NB / 4)            // 312,500 packed count words
#define NCHUNKA ((NWORDS + 1023) / 1024)   // 306 scanA blocks (4096 counts each)
#define GPANELS 391     // ceil(50000/128) row panels in gemm
#define NSHAD 8         // shadow copies for reduce atomics

typedef __bf16 bf16;
typedef __bf16 bf16x8 __attribute__((ext_vector_type(8)));
typedef __bf16 bf16x4 __attribute__((ext_vector_type(4)));
typedef float floatx4 __attribute__((ext_vector_type(4)));

// ---------------- prep: cast x & w to bf16, zero cnt32 + stat buffers ----------------
__global__ void prep_kernel(const float* __restrict__ x, bf16* __restrict__ xb,
                            const float* __restrict__ w, bf16* __restrict__ wb,
                            int4* __restrict__ cnt4, float4* __restrict__ stats4,
                            int n4x, int n4w) {
    int i = blockIdx.x * blockDim.x + threadIdx.x;
    if (i < n4x) {
        float4 v = reinterpret_cast<const float4*>(x)[i];
        bf16x4 o;
        o[0] = (bf16)v.x; o[1] = (bf16)v.y; o[2] = (bf16)v.z; o[3] = (bf16)v.w;
        reinterpret_cast<bf16x4*>(xb)[i] = o;
    }
    if (i < n4w) {
        float4 v = reinterpret_cast<const float4*>(w)[i];
        bf16x4 o;
        o[0] = (bf16)v.x; o[1] = (bf16)v.y; o[2] = (bf16)v.z; o[3] = (bf16)v.w;
        reinterpret_cast<bf16x4*>(wb)[i] = o;
    }
    if (i < NWORDS / 4) cnt4[i] = make_int4(0, 0, 0, 0);  // 1.25 MB packed counters
    // colsumS[4096 floats] + totsqS[8] + done: 1028 float4 covers all
    if (i < 1028) stats4[i] = make_float4(0.f, 0.f, 0.f, 0.f);
}

// ---------------- hist + rank: ONE atomic per edge, returns within-bucket rank -------
// Counts are Poisson lambda=1.28 (max ~15 << 255), so 4 byte-counters share a word.
// atomicAdd(1<<lane) cannot carry across bytes; the returned old byte = this edge's
// stable rank within its bucket -> scatter needs NO atomics.
__global__ void hist_kernel(const int* __restrict__ rows, const int* __restrict__ cols,
                            uint32_t* __restrict__ cnt32, uint8_t* __restrict__ rank, int E) {
    int i = blockIdx.x * blockDim.x + threadIdx.x;
    if (i < E) {
        int key = rows[i] * NT + (cols[i] >> 11);
        int sh = (key & 3) * 8;
        uint32_t old = atomicAdd(&cnt32[key >> 2], 1u << sh);
        rank[i] = (uint8_t)((old >> sh) & 0xFFu);
    }
}

// scanA: byte-packed input. Block = 1024 threads x 1 word (4 counts) = 4096 counts.
__global__ __launch_bounds__(1024) void scanA_kernel(const uint32_t* __restrict__ cnt32,
                                                     int* __restrict__ row_start,
                                                     int* __restrict__ blksum) {
    const int t = threadIdx.x;
    const int w = blockIdx.x * 1024 + t;
    uint32_t pk = (w < NWORDS) ? cnt32[w] : 0u;
    const int c0 = pk & 0xFF, c1 = (pk >> 8) & 0xFF, c2 = (pk >> 16) & 0xFF, c3 = (pk >> 24) & 0xFF;
    const int tsum = c0 + c1 + c2 + c3;
    int s = tsum;
#pragma unroll
    for (int off = 1; off < 64; off <<= 1) {
        int u = __shfl_up(s, off, 64);
        if ((t & 63) >= off) s += u;
    }
    __shared__ int wsum[16];
    if ((t & 63) == 63) wsum[t >> 6] = s;
    __syncthreads();
    if (t < 16) {
        int v = wsum[t];
#pragma unroll
        for (int off = 1; off < 16; off <<= 1) {
            int u = __shfl_up(v, off, 16);
            if (t >= off) v += u;
        }
        wsum[t] = v;
    }
    __syncthreads();
    const int base = (t >= 64) ? wsum[(t >> 6) - 1] : 0;
    const int excl = base + s - tsum;
    if (w < NWORDS) {
        const int i0 = w * 4;
        row_start[i0 + 0] = excl;
        row_start[i0 + 1] = excl + c0;
        row_start[i0 + 2] = excl + c0 + c1;
        row_start[i0 + 3] = excl + c0 + c1 + c2;
    }
    if (t == 1023) blksum[blockIdx.x] = base + s;  // chunk total
}

__global__ __launch_bounds__(1024) void scanB_kernel(const int* __restrict__ blksum,
                                                     int* __restrict__ blkoff, int nb) {
    __shared__ int s[1024];
    const int t = threadIdx.x;
    const int base = t * 2;
    int a = (base < nb) ? blksum[base] : 0;
    int b = (base + 1 < nb) ? blksum[base + 1] : 0;
    s[t] = a + b;
    __syncthreads();
    for (int off = 1; off < 1024; off <<= 1) {
        int u = (t >= off) ? s[t - off] : 0;
        __syncthreads();
        s[t] += u;
        __syncthreads();
    }
    int excl = (t == 0) ? 0 : s[t - 1];
    if (base < nb) blkoff[base] = excl;
    if (base + 1 < nb) blkoff[base + 1] = excl + a;
}

// scanC: add chunk offsets (chunk = 4096 counts -> i>>12); set sentinel.
__global__ __launch_bounds__(1024) void scanC_kernel(int* __restrict__ row_start,
                                                     const int* __restrict__ blkoff, int n) {
    int i = blockIdx.x * 1024 + threadIdx.x;
    if (i >= n) return;
    row_start[i] += blkoff[i >> 12];
    if (i == n - 1) row_start[n] = N_EDGES;
}

// scatter: NO atomics — position = row_start[key] + rank (row_start stays pristine).
__global__ void scatter_kernel(const int* __restrict__ rows, const int* __restrict__ cols,
                               const float* __restrict__ vals, const int* __restrict__ row_start,
                               const uint8_t* __restrict__ rank, int2* __restrict__ ecv, int E) {
    int i = blockIdx.x * blockDim.x + threadIdx.x;
    if (i >= E) return;
    int c = cols[i];
    int key = rows[i] * NT + (c >> 11);
    int p = row_start[key] + rank[i];
    ecv[p] = make_int2(c, __float_as_int(vals[i]));
}

// ---------------- GEMM (R10 single-buffer, measured ~80us) ----------------
__global__ __launch_bounds__(256) void gemm_kernel(const bf16* __restrict__ A,
                                                   const bf16* __restrict__ B,
                                                   bf16* __restrict__ C) {
    __shared__ bf16 lA[128 * 32];
    __shared__ bf16 lB[128 * 32];
    const int d = blockIdx.x;
    const int p = (d & 7) + ((d >> 5) << 3);  // row panel (XCD-chunked swizzle)
    const int c = (d >> 3) & 3;               // col tile
    if (p >= GPANELS) return;
    const int t = threadIdx.x;
    const int wave = t >> 6;
    const int lane = t & 63;
    const int rowBase = p * 128;
    const int colBase = c * 128;
    const int wm = (wave >> 1) * 64;
    const int wn = (wave & 1) * 64;
    floatx4 acc[4][4] = {};

    const int r_a = t >> 2;
    const int kk = (t & 3) * 8;
    const int l15 = lane & 15;
    const int koff = (lane >> 4) * 8;

    for (int k0 = 0; k0 < DIM; k0 += 32) {
#pragma unroll
        for (int j = 0; j < 2; j++) {
            int row = rowBase + r_a + j * 64;
            if (row > N_NODES - 1) row = N_NODES - 1;
            const bf16* g = A + (size_t)row * DIM + k0 + kk;
            bf16* l = lA + wave * 512 + j * 2048;
            __builtin_amdgcn_global_load_lds(
                (const __attribute__((address_space(1))) void*)g,
                (__attribute__((address_space(3))) void*)l, 16, 0, 0);
        }
#pragma unroll
        for (int j = 0; j < 2; j++) {
            int row = colBase + r_a + j * 64;
            const bf16* g = B + (size_t)row * DIM + k0 + kk;
            bf16* l = lB + wave * 512 + j * 2048;
            __builtin_amdgcn_global_load_lds(
                (const __attribute__((address_space(1))) void*)g,
                (__attribute__((address_space(3))) void*)l, 16, 0, 0);
        }
        __syncthreads();
        bf16x8 af[4], bfr[4];
#pragma unroll
        for (int i = 0; i < 4; i++)
            af[i] = *reinterpret_cast<const bf16x8*>(lA + (wm + i * 16 + l15) * 32 + koff);
#pragma unroll
        for (int j = 0; j < 4; j++)
            bfr[j] = *reinterpret_cast<const bf16x8*>(lB + (wn + j * 16 + l15) * 32 + koff);
#pragma unroll
        for (int i = 0; i < 4; i++)
#pragma unroll
            for (int j = 0; j < 4; j++)
                acc[i][j] = __builtin_amdgcn_mfma_f32_16x16x32_bf16(af[i], bfr[j], acc[i][j], 0, 0, 0);
        __syncthreads();
    }
    const int rquad = (lane >> 4) * 4;
#pragma unroll
    for (int i = 0; i < 4; i++) {
#pragma unroll
        for (int reg = 0; reg < 4; reg++) {
            int gr = rowBase + wm + i * 16 + rquad + reg;
            if (gr >= N_NODES) continue;
#pragma unroll
            for (int j = 0; j < 4; j++) {
                int gc = colBase + wn + j * 16 + l15;
                C[(size_t)gr * DIM + gc] = (bf16)acc[i][j][reg];
            }
        }
    }
}

// ---------------- SpMM (v1, measured best ~228us) ----------------
__device__ __forceinline__ float blo(uint32_t w) { return __uint_as_float(w << 16); }
__device__ __forceinline__ float bhi(uint32_t w) { return __uint_as_float(w & 0xffff0000u); }

__device__ __forceinline__ void fmac8(float* acc, float v, const uint4& w) {
    acc[0] += v * blo(w.x); acc[1] += v * bhi(w.x);
    acc[2] += v * blo(w.y); acc[3] += v * bhi(w.y);
    acc[4] += v * blo(w.z); acc[5] += v * bhi(w.z);
    acc[6] += v * blo(w.w); acc[7] += v * bhi(w.w);
}

__global__ __launch_bounds__(256) void spmm_kernel(const int* __restrict__ row_start,
                                                   const int2* __restrict__ ecv,
                                                   const bf16* __restrict__ y,
                                                   float* __restrict__ y2) {
    const int wave = threadIdx.x >> 6;
    const int lane = threadIdx.x & 63;
    const int r = blockIdx.x * 4 + wave;  // grid = 12500 exactly
    const int s = row_start[r * NT];
    const int e = row_start[(r + 1) * NT];
    float acc[8] = {0.f, 0.f, 0.f, 0.f, 0.f, 0.f, 0.f, 0.f};
    const uint32_t* yb = reinterpret_cast<const uint32_t*>(y);

    int i = s;
    for (; i + 3 < e; i += 4) {
        int2 e0 = ecv[i], e1 = ecv[i + 1], e2 = ecv[i + 2], e3 = ecv[i + 3];
        uint4 w0 = *reinterpret_cast<const uint4*>(yb + (size_t)e0.x * 256 + lane * 4);
        uint4 w1 = *reinterpret_cast<const uint4*>(yb + (size_t)e1.x * 256 + lane * 4);
        uint4 w2 = *reinterpret_cast<const uint4*>(yb + (size_t)e2.x * 256 + lane * 4);
        uint4 w3 = *reinterpret_cast<const uint4*>(yb + (size_t)e3.x * 256 + lane * 4);
        fmac8(acc, __int_as_float(e0.y), w0);
        fmac8(acc, __int_as_float(e1.y), w1);
        fmac8(acc, __int_as_float(e2.y), w2);
        fmac8(acc, __int_as_float(e3.y), w3);
    }
    for (; i < e; i++) {
        int2 e0 = ecv[i];
        uint4 w0 = *reinterpret_cast<const uint4*>(yb + (size_t)e0.x * 256 + lane * 4);
        fmac8(acc, __int_as_float(e0.y), w0);
    }
    float4* out = reinterpret_cast<float4*>(y2 + (size_t)r * DIM + lane * 8);
    out[0] = make_float4(acc[0], acc[1], acc[2], acc[3]);
    out[1] = make_float4(acc[4], acc[5], acc[6], acc[7]);
}

// ---------------- reduction + fused scalar (last-block ticket; R12-proven) ----------
#define RED_GRID 512
#define RED_CHUNK 16
__global__ __launch_bounds__(256) void reduce_kernel(const float* __restrict__ y2,
                                                     float* __restrict__ colsumS,
                                                     float* __restrict__ totsqS,
                                                     int* __restrict__ done,
                                                     const float* __restrict__ scale,
                                                     float* __restrict__ sfac,
                                                     float* __restrict__ colsum) {
    const int t = threadIdx.x;
    const int d2 = t * 2;
    float c0 = 0.f, c1 = 0.f, sq = 0.f;
    for (int r0 = blockIdx.x * RED_CHUNK; r0 < N_NODES; r0 += RED_GRID * RED_CHUNK) {
        float2 v[RED_CHUNK];
#pragma unroll
        for (int j = 0; j < RED_CHUNK; j++) {
            int r = r0 + j;
            v[j] = (r < N_NODES)
                       ? *reinterpret_cast<const float2*>(y2 + (size_t)r * DIM + d2)
                       : make_float2(0.f, 0.f);
        }
#pragma unroll
        for (int j = 0; j < RED_CHUNK; j++) {
            c0 += v[j].x;
            c1 += v[j].y;
            sq += v[j].x * v[j].x + v[j].y * v[j].y;
        }
    }
    const int sh = blockIdx.x & (NSHAD - 1);
    atomicAdd(&colsumS[sh * DIM + d2], c0);
    atomicAdd(&colsumS[sh * DIM + d2 + 1], c1);
    __shared__ float ssq[256];
    ssq[t] = sq;
    __syncthreads();
    for (int off = 128; off > 0; off >>= 1) {
        if (t < off) ssq[t] += ssq[t + off];
        __syncthreads();
    }
    if (t == 0) atomicAdd(&totsqS[sh], ssq[0]);

    __threadfence();
    __shared__ int ticket_s;
    if (t == 0) ticket_s = atomicAdd(done, 1);
    __syncthreads();
    if (ticket_s != RED_GRID - 1) return;
    float s0 = 0.f, s1 = 0.f;
#pragma unroll
    for (int c = 0; c < NSHAD; c++) {
        s0 += atomicAdd(&colsumS[c * DIM + t], 0.f);
        s1 += atomicAdd(&colsumS[c * DIM + t + 256], 0.f);
    }
    colsum[t] = s0;
    colsum[t + 256] = s1;
    float mu0 = s0 * (1.0f / N_NODES);
    float mu1 = s1 * (1.0f / N_NODES);
    __syncthreads();
    ssq[t] = mu0 * mu0 + mu1 * mu1;
    __syncthreads();
    for (int off = 128; off > 0; off >>= 1) {
        if (t < off) ssq[t] += ssq[t + off];
        __syncthreads();
    }
    if (t == 0) {
        float tq = 0.f;
#pragma unroll
        for (int c = 0; c < NSHAD; c++) tq += atomicAdd(&totsqS[c], 0.f);
        float var = tq * (1.0f / N_NODES) - ssq[0];
        sfac[0] = rsqrtf(var) * (1.0f + scale[0]) * sqrtf((float)DIM);
    }
}

// ---------------- final: out = relu((y2 - mu) * s) + x ----------------
__global__ void final_kernel(float* __restrict__ y2, const float* __restrict__ x,
                             const float* __restrict__ colsum, const float* __restrict__ sfac,
                             int n4) {
    int i = blockIdx.x * blockDim.x + threadIdx.x;
    if (i >= n4) return;
    const float invN = 1.0f / N_NODES;
    float4 v = reinterpret_cast<float4*>(y2)[i];
    float4 xv = reinterpret_cast<const float4*>(x)[i];
    float4 mu = reinterpret_cast<const float4*>(colsum)[i & 127];
    float s = sfac[0];
    v.x = fmaxf((v.x - mu.x * invN) * s, 0.0f) + xv.x;
    v.y = fmaxf((v.y - mu.y * invN) * s, 0.0f) + xv.y;
    v.z = fmaxf((v.z - mu.z * invN) * s, 0.0f) + xv.z;
    v.w = fmaxf((v.w - mu.w * invN) * s, 0.0f) + xv.w;
    reinterpret_cast<float4*>(y2)[i] = v;
}

extern "C" void kernel_launch(void* const* d_in, const int* in_sizes, int n_in,
                              void* d_out, int out_size, void* d_ws, size_t ws_size,
                              hipStream_t stream) {
    const float* x        = (const float*)d_in[0];
    const int*   adj_rows = (const int*)d_in[1];
    const int*   adj_cols = (const int*)d_in[2];
    const float* adj_vals = (const float*)d_in[3];
    const float* weight   = (const float*)d_in[4];
    const float* scale    = (const float*)d_in[5];
    float* out = (float*)d_out;  // doubles as y2 buffer

    char* ws = (char*)d_ws;
    size_t off = 0;
    auto alloc = [&](size_t b) {
        char* p = ws + off;
        off += (b + 255) & ~(size_t)255;
        return p;
    };
    bf16*    xb        = (bf16*)alloc((size_t)N_NODES * DIM * 2);   // 51.2 MB
    int2*    ecv       = (int2*)xb;  // ALIAS: gemm (reader of xb) completes before scatter writes
    bf16*    Wb        = (bf16*)alloc((size_t)DIM * DIM * 2);       // 0.5 MB
    bf16*    y         = (bf16*)alloc((size_t)N_NODES * DIM * 2);   // 51.2 MB
    uint32_t* cnt32    = (uint32_t*)alloc((size_t)NWORDS * 4);      // 1.25 MB packed counters
    uint8_t* rank      = (uint8_t*)alloc((size_t)N_EDGES);          // 1.6 MB edge ranks
    int*     row_start = (int*)alloc((size_t)(NB + 1) * 4);         // 5 MB (pristine after scanC)
    int*     blksum    = (int*)alloc((size_t)NCHUNKA * 4);
    int*     blkoff    = (int*)alloc((size_t)NCHUNKA * 4);
    float*   colsumS   = (float*)alloc((size_t)NSHAD * DIM * 4);    // 16 KB
    float*   totsqS    = (float*)alloc((size_t)NSHAD * 4);          // done lives after totsqS
    int*     done      = (int*)(totsqS + NSHAD);
    float*   colsum    = (float*)alloc(512 * 4);
    float*   sfac      = (float*)alloc(4);
    (void)ws_size; (void)in_sizes; (void)n_in; (void)out_size;

    const int n4x = N_NODES * DIM / 4;  // 6,400,000
    const int n4w = DIM * DIM / 4;      // 65,536

    // 1) casts + cnt zero + stats/done zero
    prep_kernel<<<(n4x + 255) / 256, 256, 0, stream>>>(x, xb, weight, Wb,
                                                       (int4*)cnt32, (float4*)colsumS,
                                                       n4x, n4w);

    // 2) GEMM (frees xb so ecv can alias it during scatter)
    gemm_kernel<<<1568, 256, 0, stream>>>(xb, Wb, y);

    // 3) CSR build, split kernels (coop fusion was 5x slower — R13)
    hist_kernel<<<(N_EDGES + 255) / 256, 256, 0, stream>>>(adj_rows, adj_cols, cnt32, rank, N_EDGES);
    scanA_kernel<<<NCHUNKA, 1024, 0, stream>>>(cnt32, row_start, blksum);
    scanB_kernel<<<1, 1024, 0, stream>>>(blksum, blkoff, NCHUNKA);
    scanC_kernel<<<(NB + 1023) / 1024, 1024, 0, stream>>>(row_start, blkoff, NB);
    scatter_kernel<<<(N_EDGES + 255) / 256, 256, 0, stream>>>(adj_rows, adj_cols, adj_vals,
                                                              row_start, rank, ecv, N_EDGES);

    // 4) SpMM
    spmm_kernel<<<N_NODES / 4, 256, 0, stream>>>(row_start, ecv, y, out);

    // 5) reduce + fused scalar
    reduce_kernel<<<RED_GRID, 256, 0, stream>>>(out, colsumS, totsqS, done, scale, sfac, colsum);

    // 6) final
    final_kernel<<<(n4x + 255) / 256, 256, 0, stream>>>(out, x, colsum, sfac, n4x);
}